// Round 7
// baseline (39.647 us; speedup 1.0000x reference)
//
#include <hip/hip_runtime.h>
#include <math.h>

#define NPTS 4096
#define BLOCK 256
#define PTS4 (NPTS / 2)            // 2048 float4 (2 points each)
#define ITERS (PTS4 / BLOCK)       // 8 float4 per thread
#define BPB 8                      // batches per block (pipelined)

// Multi-batch pipelined block: while pass-2 (sqrt from LDS) of batch j runs,
// batch j+1's global loads are already in flight into registers (pn[]).
// Single 32 KiB LDS buffer (holds only the pass-2 batch); wred is
// parity-double-buffered so epilogue(j) never races stage(j+1).
__global__ __launch_bounds__(BLOCK, 4) void geo_mlp_kernel(
    const float* __restrict__ points,  // (B, N, 2)
    const float* __restrict__ W1,      // (10, 64)
    const float* __restrict__ b1,      // (64)
    const float* __restrict__ W2,      // (64, 32)
    const float* __restrict__ b2,      // (32)
    float* __restrict__ out)           // (B, 32)
{
    __shared__ float4 pts[PTS4];       // 32 KiB stage (current pass-2 batch)
    __shared__ float wred[2][4][9];    // parity-buffered per-wave partials
    __shared__ float h[64];            // hidden layer (wave 0 only)

    const int tid  = threadIdx.x;
    const int lane = tid & 63;
    const int wave = tid >> 6;
    const size_t b0 = (size_t)blockIdx.x * BPB;

    // ---- wave 0: preload MLP weights into registers (issue EARLY) ----
    float w1r[10];                     // W1[:, lane]
    float w2r[32];                     // W2[rbase..rbase+31, lane&31]
    float b1r = 0.f, b2r = 0.f;
    const int col   = lane & 31;
    const int rbase = (lane >> 5) * 32;
    if (wave == 0) {
        #pragma unroll
        for (int i = 0; i < 10; ++i)
            w1r[i] = W1[i * 64 + lane];
        b1r = b1[lane];
        #pragma unroll
        for (int r = 0; r < 32; ++r)
            w2r[r] = W2[(rbase + r) * 32 + col];
        b2r = (lane < 32) ? b2[col] : 0.0f;  // bias counted once across halves
    }

    const float invN = 1.0f / (float)NPTS;
    float4 pn[ITERS];                  // in-flight next batch (32 VGPR)

    // issue the 8 global loads for batch j into pn (consumed later)
    auto issue_loads = [&](int j) {
        const float4* __restrict__ src =
            (const float4*)(points + (b0 + (size_t)j) * NPTS * 2);
        #pragma unroll
        for (int i = 0; i < ITERS; ++i)
            pn[i] = src[tid + i * BLOCK];
    };

    // consume pn: accumulate moments/minmax, store to LDS, reduce -> wred[par]
    auto stage = [&](int par) {
        float minx =  INFINITY, miny =  INFINITY;
        float maxx = -INFINITY, maxy = -INFINITY;
        float sx = 0.f, sy = 0.f, sxx = 0.f, syy = 0.f;
        #pragma unroll
        for (int i = 0; i < ITERS; ++i) {
            float4 v = pn[i];
            pts[tid + i * BLOCK] = v;
            minx = fminf(minx, fminf(v.x, v.z));
            maxx = fmaxf(maxx, fmaxf(v.x, v.z));
            miny = fminf(miny, fminf(v.y, v.w));
            maxy = fmaxf(maxy, fmaxf(v.y, v.w));
            sx += v.x + v.z;
            sy += v.y + v.w;
            sxx = fmaf(v.x, v.x, sxx); sxx = fmaf(v.z, v.z, sxx);
            syy = fmaf(v.y, v.y, syy); syy = fmaf(v.w, v.w, syy);
        }
        #pragma unroll
        for (int off = 32; off > 0; off >>= 1) {
            minx = fminf(minx, __shfl_down(minx, off));
            maxx = fmaxf(maxx, __shfl_down(maxx, off));
            miny = fminf(miny, __shfl_down(miny, off));
            maxy = fmaxf(maxy, __shfl_down(maxy, off));
            sx  += __shfl_down(sx,  off);
            sy  += __shfl_down(sy,  off);
            sxx += __shfl_down(sxx, off);
            syy += __shfl_down(syy, off);
        }
        if (lane == 0) {
            wred[par][wave][0] = minx; wred[par][wave][1] = maxx;
            wred[par][wave][2] = miny; wred[par][wave][3] = maxy;
            wred[par][wave][4] = sx;   wred[par][wave][5] = sy;
            wred[par][wave][6] = sxx;  wred[par][wave][7] = syy;
        }
    };

    // ---- prologue: batch 0 staged, batch 1 in flight ----
    issue_loads(0);
    stage(0);
    if (BPB > 1) issue_loads(1);
    __syncthreads();

    for (int j = 0; j < BPB; ++j) {
        const int par = j & 1;
        const float cx = ((wred[par][0][4] + wred[par][1][4]) +
                          (wred[par][2][4] + wred[par][3][4])) * invN;
        const float cy = ((wred[par][0][5] + wred[par][1][5]) +
                          (wred[par][2][5] + wred[par][3][5])) * invN;

        // ---- pass 2: sum of distances from LDS (sum(d^2) analytic) ----
        float sd = 0.f;
        #pragma unroll
        for (int i = 0; i < ITERS; ++i) {
            float4 v = pts[tid + i * BLOCK];
            float dx0 = v.x - cx, dy0 = v.y - cy;
            float dx1 = v.z - cx, dy1 = v.w - cy;
            sd += sqrtf(fmaf(dx0, dx0, dy0 * dy0));
            sd += sqrtf(fmaf(dx1, dx1, dy1 * dy1));
        }
        #pragma unroll
        for (int off = 32; off > 0; off >>= 1)
            sd += __shfl_down(sd, off);
        if (lane == 0)
            wred[par][wave][8] = sd;
        __syncthreads();   // B1: pts free for overwrite; sd partials visible

        // ---- stage next batch (overlaps its loads already in flight),
        //      issue loads for batch j+2 (hide under next pass-2) ----
        if (j + 1 < BPB) {
            stage((j + 1) & 1);
            if (j + 2 < BPB) issue_loads(j + 2);
        }

        // ---- epilogue batch j: wave 0, wave-synchronous ----
        if (wave == 0) {
            float fminx = fminf(fminf(wred[par][0][0], wred[par][1][0]),
                                fminf(wred[par][2][0], wred[par][3][0]));
            float fmaxx = fmaxf(fmaxf(wred[par][0][1], wred[par][1][1]),
                                fmaxf(wred[par][2][1], wred[par][3][1]));
            float fminy = fminf(fminf(wred[par][0][2], wred[par][1][2]),
                                fminf(wred[par][2][2], wred[par][3][2]));
            float fmaxy = fmaxf(fmaxf(wred[par][0][3], wred[par][1][3]),
                                fmaxf(wred[par][2][3], wred[par][3][3]));
            float fsxx = (wred[par][0][6] + wred[par][1][6]) +
                         (wred[par][2][6] + wred[par][3][6]);
            float fsyy = (wred[par][0][7] + wred[par][1][7]) +
                         (wred[par][2][7] + wred[par][3][7]);
            float fsd  = (wred[par][0][8] + wred[par][1][8]) +
                         (wred[par][2][8] + wred[par][3][8]);

            float dist_mean = fsd * invN;
            float ed2 = (fsxx + fsyy) * invN - (cx * cx + cy * cy);
            float dist_std = sqrtf(fmaxf(ed2 - dist_mean * dist_mean, 0.f));
            float stdx = sqrtf(fmaxf(fsxx * invN - cx * cx, 0.f));
            float stdy = sqrtf(fmaxf(fsyy * invN - cy * cy, 0.f));

            float g[10];
            g[0] = (fminx + fmaxx) * 0.5f;
            g[1] = (fminy + fmaxy) * 0.5f;
            g[2] = fmaxx - fminx;
            g[3] = fmaxy - fminy;
            g[4] = cx;
            g[5] = cy;
            g[6] = stdx;
            g[7] = stdy;
            g[8] = dist_mean;
            g[9] = dist_std;

            float acc = b1r;
            #pragma unroll
            for (int i = 0; i < 10; ++i)
                acc = fmaf(g[i], w1r[i], acc);
            h[lane] = fmaxf(acc, 0.f);

            asm volatile("s_waitcnt lgkmcnt(0)" ::: "memory");

            float acc2 = b2r;
            #pragma unroll
            for (int r = 0; r < 32; ++r)
                acc2 = fmaf(h[rbase + r], w2r[r], acc2);
            acc2 += __shfl_down(acc2, 32);
            if (lane < 32)
                out[(b0 + (size_t)j) * 32 + lane] = fmaxf(acc2, 0.f);
        }
        __syncthreads();   // B2: wred[(j+1)&1] visible; pts ready for pass2
    }
}

extern "C" void kernel_launch(void* const* d_in, const int* in_sizes, int n_in,
                              void* d_out, int out_size, void* d_ws, size_t ws_size,
                              hipStream_t stream) {
    const float* points = (const float*)d_in[0];
    const float* W1     = (const float*)d_in[1];
    const float* b1     = (const float*)d_in[2];
    const float* W2     = (const float*)d_in[3];
    const float* b2     = (const float*)d_in[4];
    float* out          = (float*)d_out;

    const int B = in_sizes[0] / (NPTS * 2);   // 4096
    geo_mlp_kernel<<<B / BPB, BLOCK, 0, stream>>>(points, W1, b1, W2, b2, out);
}

// Round 8
// 30.306 us; speedup vs baseline: 1.3082x; 1.3082x over previous
//
#include <hip/hip_runtime.h>
#include <math.h>

#define NPTS 4096
#define PTS4 (NPTS / 2)      // 2048 float4 per batch (2 points each)
#define LPL  (PTS4 / 64)     // 32 float4 per lane = 128 VGPRs

// One WAVE per batch, zero LDS, zero barriers. The whole 32 KiB batch lives
// in registers; all reductions are xor-butterflies (every lane holds the
// result); the MLP runs per-wave with layer-2 row gather via __shfl.
// ~195 VGPR -> 2 waves/SIMD = 8 independent waves/CU, each with 32 KiB of
// loads in flight; FIFO memory service self-staggers their compute phases
// so the HBM pipe never idles (no block-wide barrier convoy).
__global__ __launch_bounds__(64, 2) void geo_mlp_kernel(
    const float* __restrict__ points,  // (B, N, 2)
    const float* __restrict__ W1,      // (10, 64)
    const float* __restrict__ b1,      // (64)
    const float* __restrict__ W2,      // (64, 32)
    const float* __restrict__ b2,      // (32)
    float* __restrict__ out)           // (B, 32)
{
    const int lane  = threadIdx.x;     // single-wave block: 0..63
    const size_t b  = blockIdx.x;

    const float4* __restrict__ src =
        (const float4*)(points + b * (size_t)(NPTS * 2));

    // ---- issue the whole batch stream FIRST (32 dwordx4 in flight) ----
    float4 pn[LPL];
    #pragma unroll
    for (int i = 0; i < LPL; ++i)
        pn[i] = src[lane + i * 64];

    // ---- weights issued after: latency hides under the point stream ----
    const int col   = lane & 31;
    const int rbase = (lane >> 5) * 32;
    float w1r[10], w2r[32];
    #pragma unroll
    for (int i = 0; i < 10; ++i)
        w1r[i] = W1[i * 64 + lane];
    float b1r = b1[lane];
    #pragma unroll
    for (int r = 0; r < 32; ++r)
        w2r[r] = W2[(rbase + r) * 32 + col];
    // bias counted ONCE across the two lane halves (summed via shfl_down(32))
    float b2r = (lane < 32) ? b2[col] : 0.0f;

    // ---- pass 1: moments/minmax from registers ----
    float minx =  INFINITY, miny =  INFINITY;
    float maxx = -INFINITY, maxy = -INFINITY;
    float sx = 0.f, sy = 0.f, sxx = 0.f, syy = 0.f;
    #pragma unroll
    for (int i = 0; i < LPL; ++i) {
        float4 v = pn[i];
        minx = fminf(minx, fminf(v.x, v.z));
        maxx = fmaxf(maxx, fmaxf(v.x, v.z));
        miny = fminf(miny, fminf(v.y, v.w));
        maxy = fmaxf(maxy, fmaxf(v.y, v.w));
        sx += v.x + v.z;
        sy += v.y + v.w;
        sxx = fmaf(v.x, v.x, sxx); sxx = fmaf(v.z, v.z, sxx);
        syy = fmaf(v.y, v.y, syy); syy = fmaf(v.w, v.w, syy);
    }

    // xor butterfly: ALL lanes end up holding the full-wave totals
    #pragma unroll
    for (int m = 32; m > 0; m >>= 1) {
        minx = fminf(minx, __shfl_xor(minx, m));
        maxx = fmaxf(maxx, __shfl_xor(maxx, m));
        miny = fminf(miny, __shfl_xor(miny, m));
        maxy = fmaxf(maxy, __shfl_xor(maxy, m));
        sx  += __shfl_xor(sx,  m);
        sy  += __shfl_xor(sy,  m);
        sxx += __shfl_xor(sxx, m);
        syy += __shfl_xor(syy, m);
    }

    const float invN = 1.0f / (float)NPTS;
    const float cx = sx * invN;
    const float cy = sy * invN;

    // ---- pass 2: sum of distances from registers (sum(d^2) analytic) ----
    float sd = 0.f;
    #pragma unroll
    for (int i = 0; i < LPL; ++i) {
        float4 v = pn[i];
        float dx0 = v.x - cx, dy0 = v.y - cy;
        float dx1 = v.z - cx, dy1 = v.w - cy;
        sd += sqrtf(fmaf(dx0, dx0, dy0 * dy0));
        sd += sqrtf(fmaf(dx1, dx1, dy1 * dy1));
    }
    #pragma unroll
    for (int m = 32; m > 0; m >>= 1)
        sd += __shfl_xor(sd, m);

    // ---- geo features (every lane redundantly; cheap) ----
    float dist_mean = sd * invN;
    float ed2 = (sxx + syy) * invN - (cx * cx + cy * cy);   // E[d^2]
    float dist_std = sqrtf(fmaxf(ed2 - dist_mean * dist_mean, 0.f));
    float stdx = sqrtf(fmaxf(sxx * invN - cx * cx, 0.f));
    float stdy = sqrtf(fmaxf(syy * invN - cy * cy, 0.f));

    float g[10];
    g[0] = (minx + maxx) * 0.5f;   // bbox_center.x
    g[1] = (miny + maxy) * 0.5f;   // bbox_center.y
    g[2] = maxx - minx;            // bbox_size.x
    g[3] = maxy - miny;            // bbox_size.y
    g[4] = cx;                     // centroid.x
    g[5] = cy;                     // centroid.y
    g[6] = stdx;                   // std.x
    g[7] = stdy;                   // std.y
    g[8] = dist_mean;
    g[9] = dist_std;

    // ---- MLP layer 1: lane l -> hidden unit l ----
    float hval = b1r;
    #pragma unroll
    for (int i = 0; i < 10; ++i)
        hval = fmaf(g[i], w1r[i], hval);
    hval = fmaxf(hval, 0.f);

    // ---- MLP layer 2: row gather via shfl (no LDS) ----
    float acc2 = b2r;
    #pragma unroll
    for (int r = 0; r < 32; ++r)
        acc2 = fmaf(__shfl(hval, rbase + r), w2r[r], acc2);
    acc2 += __shfl_down(acc2, 32);   // add rows 32..63 partial
    if (lane < 32)
        out[b * 32 + lane] = fmaxf(acc2, 0.f);
}

extern "C" void kernel_launch(void* const* d_in, const int* in_sizes, int n_in,
                              void* d_out, int out_size, void* d_ws, size_t ws_size,
                              hipStream_t stream) {
    const float* points = (const float*)d_in[0];
    const float* W1     = (const float*)d_in[1];
    const float* b1     = (const float*)d_in[2];
    const float* W2     = (const float*)d_in[3];
    const float* b2     = (const float*)d_in[4];
    float* out          = (float*)d_out;

    const int B = in_sizes[0] / (NPTS * 2);   // 4096
    geo_mlp_kernel<<<B, 64, 0, stream>>>(points, W1, b1, W2, b2, out);
}

// Round 9
// 26.881 us; speedup vs baseline: 1.4749x; 1.1274x over previous
//
#include <hip/hip_runtime.h>
#include <math.h>

#define NPTS 4096
#define BLOCK 256
#define PTS4 (NPTS / 2)            // 2048 float4 (2 points each)
#define ITERS (PTS4 / BLOCK)       // 8

// R6 (best, 28.8us) + raw-HW sqrt: sqrtf default codegen is the IEEE
// scale+newton sequence (~10 inst); __builtin_amdgcn_sqrtf emits bare
// v_sqrt_f32 (~1 ulp — absmax budget 3.4e-2 dwarfs it). Pass 2's 16
// sqrts/thread sit in the non-overlapped phase between barriers, so this
// directly shrinks the serial tail.
__global__ __launch_bounds__(BLOCK, 4) void geo_mlp_kernel(
    const float* __restrict__ points,  // (B, N, 2)
    const float* __restrict__ W1,      // (10, 64)
    const float* __restrict__ b1,      // (64)
    const float* __restrict__ W2,      // (64, 32)
    const float* __restrict__ b2,      // (32)
    float* __restrict__ out)           // (B, 32)
{
    __shared__ float4 pts[PTS4];       // 32 KiB point stage
    __shared__ float wred[4][9];       // per-wave partials
    __shared__ float h[64];            // hidden layer

    const int tid  = threadIdx.x;
    const int lane = tid & 63;
    const int wave = tid >> 6;
    const int b    = blockIdx.x;

    // ---- wave 0: preload MLP weights into registers (issue EARLY) ----
    float w1r[10];                     // W1[:, lane]
    float w2r[32];                     // W2[rbase..rbase+31, lane&31]
    float b1r = 0.f, b2r = 0.f;
    const int col   = lane & 31;
    const int rbase = (lane >> 5) * 32;
    if (wave == 0) {
        #pragma unroll
        for (int i = 0; i < 10; ++i)
            w1r[i] = W1[i * 64 + lane];
        b1r = b1[lane];
        #pragma unroll
        for (int r = 0; r < 32; ++r)
            w2r[r] = W2[(rbase + r) * 32 + col];
        // bias counted ONCE across the two lane halves (summed via shfl_down(32))
        b2r = (lane < 32) ? b2[col] : 0.0f;
    }

    const float4* __restrict__ src =
        (const float4*)(points + (size_t)b * NPTS * 2);

    // ---- pass 1: global -> LDS stage + moment/minmax accumulation ----
    float minx =  INFINITY, miny =  INFINITY;
    float maxx = -INFINITY, maxy = -INFINITY;
    float sx = 0.f, sy = 0.f, sxx = 0.f, syy = 0.f;

    #pragma unroll
    for (int i = 0; i < ITERS; ++i) {
        const int idx = tid + i * BLOCK;
        float4 v = src[idx];
        pts[idx] = v;
        minx = fminf(minx, fminf(v.x, v.z));
        maxx = fmaxf(maxx, fmaxf(v.x, v.z));
        miny = fminf(miny, fminf(v.y, v.w));
        maxy = fmaxf(maxy, fmaxf(v.y, v.w));
        sx += v.x + v.z;
        sy += v.y + v.w;
        sxx = fmaf(v.x, v.x, sxx); sxx = fmaf(v.z, v.z, sxx);
        syy = fmaf(v.y, v.y, syy); syy = fmaf(v.w, v.w, syy);
    }

    // wave (64-lane) butterfly reduction
    #pragma unroll
    for (int off = 32; off > 0; off >>= 1) {
        minx = fminf(minx, __shfl_down(minx, off));
        maxx = fmaxf(maxx, __shfl_down(maxx, off));
        miny = fminf(miny, __shfl_down(miny, off));
        maxy = fmaxf(maxy, __shfl_down(maxy, off));
        sx  += __shfl_down(sx,  off);
        sy  += __shfl_down(sy,  off);
        sxx += __shfl_down(sxx, off);
        syy += __shfl_down(syy, off);
    }
    if (lane == 0) {
        wred[wave][0] = minx; wred[wave][1] = maxx;
        wred[wave][2] = miny; wred[wave][3] = maxy;
        wred[wave][4] = sx;   wred[wave][5] = sy;
        wred[wave][6] = sxx;  wred[wave][7] = syy;
    }
    __syncthreads();

    // pass 2 needs ONLY the centroid — everything else combined in epilogue
    const float invN = 1.0f / (float)NPTS;
    const float cx = ((wred[0][4] + wred[1][4]) + (wred[2][4] + wred[3][4])) * invN;
    const float cy = ((wred[0][5] + wred[1][5]) + (wred[2][5] + wred[3][5])) * invN;

    // ---- pass 2: sum of distances from LDS (sum(d^2) is analytic) ----
    float sd = 0.f;
    #pragma unroll
    for (int i = 0; i < ITERS; ++i) {
        float4 v = pts[tid + i * BLOCK];
        float dx0 = v.x - cx, dy0 = v.y - cy;
        float dx1 = v.z - cx, dy1 = v.w - cy;
        sd += __builtin_amdgcn_sqrtf(fmaf(dx0, dx0, dy0 * dy0));
        sd += __builtin_amdgcn_sqrtf(fmaf(dx1, dx1, dy1 * dy1));
    }
    #pragma unroll
    for (int off = 32; off > 0; off >>= 1)
        sd += __shfl_down(sd, off);
    if (lane == 0)
        wred[wave][8] = sd;
    __syncthreads();

    // ---- epilogue: wave 0 only, wave-synchronous (waves 1-3 retire) ----
    if (wave == 0) {
        float fminx = fminf(fminf(wred[0][0], wred[1][0]), fminf(wred[2][0], wred[3][0]));
        float fmaxx = fmaxf(fmaxf(wred[0][1], wred[1][1]), fmaxf(wred[2][1], wred[3][1]));
        float fminy = fminf(fminf(wred[0][2], wred[1][2]), fminf(wred[2][2], wred[3][2]));
        float fmaxy = fmaxf(fmaxf(wred[0][3], wred[1][3]), fmaxf(wred[2][3], wred[3][3]));
        float fsxx = (wred[0][6] + wred[1][6]) + (wred[2][6] + wred[3][6]);
        float fsyy = (wred[0][7] + wred[1][7]) + (wred[2][7] + wred[3][7]);
        float fsd  = (wred[0][8] + wred[1][8]) + (wred[2][8] + wred[3][8]);

        float dist_mean = fsd * invN;
        float ed2 = (fsxx + fsyy) * invN - (cx * cx + cy * cy);  // E[d^2]
        float dist_std  = __builtin_amdgcn_sqrtf(fmaxf(ed2 - dist_mean * dist_mean, 0.f));
        float stdx = __builtin_amdgcn_sqrtf(fmaxf(fsxx * invN - cx * cx, 0.f));
        float stdy = __builtin_amdgcn_sqrtf(fmaxf(fsyy * invN - cy * cy, 0.f));

        float g[10];
        g[0] = (fminx + fmaxx) * 0.5f;   // bbox_center.x
        g[1] = (fminy + fmaxy) * 0.5f;   // bbox_center.y
        g[2] = fmaxx - fminx;            // bbox_size.x
        g[3] = fmaxy - fminy;            // bbox_size.y
        g[4] = cx;                       // centroid.x
        g[5] = cy;                       // centroid.y
        g[6] = stdx;                     // std.x
        g[7] = stdy;                     // std.y
        g[8] = dist_mean;
        g[9] = dist_std;

        // layer 1: lane l -> hidden unit l (weights already in registers)
        float acc = b1r;
        #pragma unroll
        for (int i = 0; i < 10; ++i)
            acc = fmaf(g[i], w1r[i], acc);
        h[lane] = fmaxf(acc, 0.f);

        // same-wave LDS write->read: drain LDS queue, block reordering
        asm volatile("s_waitcnt lgkmcnt(0)" ::: "memory");

        // layer 2: lane l -> col l&31, rows rbase..rbase+31 from registers
        float acc2 = b2r;
        #pragma unroll
        for (int r = 0; r < 32; ++r)
            acc2 = fmaf(h[rbase + r], w2r[r], acc2);
        acc2 += __shfl_down(acc2, 32);   // add rows 32..63 partial
        if (lane < 32)
            out[(size_t)b * 32 + lane] = fmaxf(acc2, 0.f);
    }
}

extern "C" void kernel_launch(void* const* d_in, const int* in_sizes, int n_in,
                              void* d_out, int out_size, void* d_ws, size_t ws_size,
                              hipStream_t stream) {
    const float* points = (const float*)d_in[0];
    const float* W1     = (const float*)d_in[1];
    const float* b1     = (const float*)d_in[2];
    const float* W2     = (const float*)d_in[3];
    const float* b2     = (const float*)d_in[4];
    float* out          = (float*)d_out;

    const int B = in_sizes[0] / (NPTS * 2);   // 4096
    geo_mlp_kernel<<<B, BLOCK, 0, stream>>>(points, W1, b1, W2, b2, out);
}

// Round 10
// 26.382 us; speedup vs baseline: 1.5028x; 1.0189x over previous
//
#include <hip/hip_runtime.h>
#include <math.h>

#define NPTS 4096
#define BLOCK 256
#define PTS4 (NPTS / 2)            // 2048 float4 (2 points each)
#define ITERS (PTS4 / BLOCK)       // 8 float4 per thread = 32 VGPR

// R9 (26.9us) minus the LDS point stage: pass 2 re-reads exactly the elements
// the SAME thread wrote (pts was a manual spill, not communication), so the
// batch lives in registers. (256,4) -> 128-VGPR cap, ~90 used, no scratch.
// Fast v_sqrt_f32 + hoisted weights + wave-0 epilogue retained from R9.
__global__ __launch_bounds__(BLOCK, 4) void geo_mlp_kernel(
    const float* __restrict__ points,  // (B, N, 2)
    const float* __restrict__ W1,      // (10, 64)
    const float* __restrict__ b1,      // (64)
    const float* __restrict__ W2,      // (64, 32)
    const float* __restrict__ b2,      // (32)
    float* __restrict__ out)           // (B, 32)
{
    __shared__ float wred[4][9];       // per-wave partials
    __shared__ float h[64];            // hidden layer

    const int tid  = threadIdx.x;
    const int lane = tid & 63;
    const int wave = tid >> 6;
    const int b    = blockIdx.x;

    // ---- wave 0: preload MLP weights into registers (issue EARLY) ----
    float w1r[10];                     // W1[:, lane]
    float w2r[32];                     // W2[rbase..rbase+31, lane&31]
    float b1r = 0.f, b2r = 0.f;
    const int col   = lane & 31;
    const int rbase = (lane >> 5) * 32;
    if (wave == 0) {
        #pragma unroll
        for (int i = 0; i < 10; ++i)
            w1r[i] = W1[i * 64 + lane];
        b1r = b1[lane];
        #pragma unroll
        for (int r = 0; r < 32; ++r)
            w2r[r] = W2[(rbase + r) * 32 + col];
        // bias counted ONCE across the two lane halves (summed via shfl_down(32))
        b2r = (lane < 32) ? b2[col] : 0.0f;
    }

    const float4* __restrict__ src =
        (const float4*)(points + (size_t)b * NPTS * 2);

    // ---- single HBM pass into registers ----
    float4 p[ITERS];
    #pragma unroll
    for (int i = 0; i < ITERS; ++i)
        p[i] = src[tid + i * BLOCK];

    float minx =  INFINITY, miny =  INFINITY;
    float maxx = -INFINITY, maxy = -INFINITY;
    float sx = 0.f, sy = 0.f, sxx = 0.f, syy = 0.f;

    #pragma unroll
    for (int i = 0; i < ITERS; ++i) {
        float4 v = p[i];
        minx = fminf(minx, fminf(v.x, v.z));
        maxx = fmaxf(maxx, fmaxf(v.x, v.z));
        miny = fminf(miny, fminf(v.y, v.w));
        maxy = fmaxf(maxy, fmaxf(v.y, v.w));
        sx += v.x + v.z;
        sy += v.y + v.w;
        sxx = fmaf(v.x, v.x, sxx); sxx = fmaf(v.z, v.z, sxx);
        syy = fmaf(v.y, v.y, syy); syy = fmaf(v.w, v.w, syy);
    }

    // wave (64-lane) butterfly reduction
    #pragma unroll
    for (int off = 32; off > 0; off >>= 1) {
        minx = fminf(minx, __shfl_down(minx, off));
        maxx = fmaxf(maxx, __shfl_down(maxx, off));
        miny = fminf(miny, __shfl_down(miny, off));
        maxy = fmaxf(maxy, __shfl_down(maxy, off));
        sx  += __shfl_down(sx,  off);
        sy  += __shfl_down(sy,  off);
        sxx += __shfl_down(sxx, off);
        syy += __shfl_down(syy, off);
    }
    if (lane == 0) {
        wred[wave][0] = minx; wred[wave][1] = maxx;
        wred[wave][2] = miny; wred[wave][3] = maxy;
        wred[wave][4] = sx;   wred[wave][5] = sy;
        wred[wave][6] = sxx;  wred[wave][7] = syy;
    }
    __syncthreads();

    // pass 2 needs ONLY the centroid — everything else combined in epilogue
    const float invN = 1.0f / (float)NPTS;
    const float cx = ((wred[0][4] + wred[1][4]) + (wred[2][4] + wred[3][4])) * invN;
    const float cy = ((wred[0][5] + wred[1][5]) + (wred[2][5] + wred[3][5])) * invN;

    // ---- pass 2: sum of distances from REGISTERS (sum(d^2) analytic) ----
    float sd = 0.f;
    #pragma unroll
    for (int i = 0; i < ITERS; ++i) {
        float4 v = p[i];
        float dx0 = v.x - cx, dy0 = v.y - cy;
        float dx1 = v.z - cx, dy1 = v.w - cy;
        sd += __builtin_amdgcn_sqrtf(fmaf(dx0, dx0, dy0 * dy0));
        sd += __builtin_amdgcn_sqrtf(fmaf(dx1, dx1, dy1 * dy1));
    }
    #pragma unroll
    for (int off = 32; off > 0; off >>= 1)
        sd += __shfl_down(sd, off);
    if (lane == 0)
        wred[wave][8] = sd;
    __syncthreads();

    // ---- epilogue: wave 0 only, wave-synchronous (waves 1-3 retire) ----
    if (wave == 0) {
        float fminx = fminf(fminf(wred[0][0], wred[1][0]), fminf(wred[2][0], wred[3][0]));
        float fmaxx = fmaxf(fmaxf(wred[0][1], wred[1][1]), fmaxf(wred[2][1], wred[3][1]));
        float fminy = fminf(fminf(wred[0][2], wred[1][2]), fminf(wred[2][2], wred[3][2]));
        float fmaxy = fmaxf(fmaxf(wred[0][3], wred[1][3]), fmaxf(wred[2][3], wred[3][3]));
        float fsxx = (wred[0][6] + wred[1][6]) + (wred[2][6] + wred[3][6]);
        float fsyy = (wred[0][7] + wred[1][7]) + (wred[2][7] + wred[3][7]);
        float fsd  = (wred[0][8] + wred[1][8]) + (wred[2][8] + wred[3][8]);

        float dist_mean = fsd * invN;
        float ed2 = (fsxx + fsyy) * invN - (cx * cx + cy * cy);  // E[d^2]
        float dist_std  = __builtin_amdgcn_sqrtf(fmaxf(ed2 - dist_mean * dist_mean, 0.f));
        float stdx = __builtin_amdgcn_sqrtf(fmaxf(fsxx * invN - cx * cx, 0.f));
        float stdy = __builtin_amdgcn_sqrtf(fmaxf(fsyy * invN - cy * cy, 0.f));

        float g[10];
        g[0] = (fminx + fmaxx) * 0.5f;   // bbox_center.x
        g[1] = (fminy + fmaxy) * 0.5f;   // bbox_center.y
        g[2] = fmaxx - fminx;            // bbox_size.x
        g[3] = fmaxy - fminy;            // bbox_size.y
        g[4] = cx;                       // centroid.x
        g[5] = cy;                       // centroid.y
        g[6] = stdx;                     // std.x
        g[7] = stdy;                     // std.y
        g[8] = dist_mean;
        g[9] = dist_std;

        // layer 1: lane l -> hidden unit l (weights already in registers)
        float acc = b1r;
        #pragma unroll
        for (int i = 0; i < 10; ++i)
            acc = fmaf(g[i], w1r[i], acc);
        h[lane] = fmaxf(acc, 0.f);

        // same-wave LDS write->read: drain LDS queue, block reordering
        asm volatile("s_waitcnt lgkmcnt(0)" ::: "memory");

        // layer 2: lane l -> col l&31, rows rbase..rbase+31 from registers
        float acc2 = b2r;
        #pragma unroll
        for (int r = 0; r < 32; ++r)
            acc2 = fmaf(h[rbase + r], w2r[r], acc2);
        acc2 += __shfl_down(acc2, 32);   // add rows 32..63 partial
        if (lane < 32)
            out[(size_t)b * 32 + lane] = fmaxf(acc2, 0.f);
    }
}

extern "C" void kernel_launch(void* const* d_in, const int* in_sizes, int n_in,
                              void* d_out, int out_size, void* d_ws, size_t ws_size,
                              hipStream_t stream) {
    const float* points = (const float*)d_in[0];
    const float* W1     = (const float*)d_in[1];
    const float* b1     = (const float*)d_in[2];
    const float* W2     = (const float*)d_in[3];
    const float* b2     = (const float*)d_in[4];
    float* out          = (float*)d_out;

    const int B = in_sizes[0] / (NPTS * 2);   // 4096
    geo_mlp_kernel<<<B, BLOCK, 0, stream>>>(points, W1, b1, W2, b2, out);
}